// Round 2
// baseline (189.132 us; speedup 1.0000x reference)
//
#include <hip/hip_runtime.h>
#include <hip/hip_bf16.h>

// ---------- problem constants ----------
#define BATCH   2
#define SEQ     2048
#define DMODEL  1024
#define NHEADS  16
#define DHEAD   64
#define MROWS   (BATCH*SEQ)     // 4096
#define NBH     (BATCH*NHEADS)  // 32

typedef float  f32x4  __attribute__((ext_vector_type(4)));
typedef short  s16x4  __attribute__((ext_vector_type(4)));
typedef short  s16x8  __attribute__((ext_vector_type(8)));
typedef __bf16 bf16x8 __attribute__((ext_vector_type(8)));

__device__ __forceinline__ short f2bf(float f) {
  union { float f; unsigned u; } v; v.f = f;
  return (short)((v.u + 0x7fffu + ((v.u >> 16) & 1u)) >> 16);  // RNE
}
__device__ __forceinline__ float bf2f(short s) {
  union { unsigned u; float f; } v; v.u = ((unsigned)(unsigned short)s) << 16;
  return v.f;
}

// ---------- fused prep: z<4 -> W transpose+bf16; z>=4 -> x fp32->bf16 -------
__global__ void prep_fused(const float* __restrict__ x, short* __restrict__ xb,
                           const float* __restrict__ Wq, const float* __restrict__ Wk,
                           const float* __restrict__ Wv, const float* __restrict__ Wo,
                           short* __restrict__ WtQKV, short* __restrict__ WtO) {
  __shared__ float t[32][33];
  int z = blockIdx.z;
  int tx = threadIdx.x, ty = threadIdx.y;           // block (32,8)
  if (z >= 4) {                                     // convert x chunk
    int blk = (z - 4) * 1024 + blockIdx.y * 32 + blockIdx.x;
    int i = (blk * 256 + ty * 32 + tx) * 4;
    float4 v = *(const float4*)(x + i);
    s16x4 o = { f2bf(v.x), f2bf(v.y), f2bf(v.z), f2bf(v.w) };
    *(s16x4*)(xb + i) = o;
    return;
  }
  const float* W; short* Wt;
  if      (z == 0) { W = Wq; Wt = WtQKV; }
  else if (z == 1) { W = Wk; Wt = WtQKV + (1u << 20); }
  else if (z == 2) { W = Wv; Wt = WtQKV + (2u << 20); }
  else             { W = Wo; Wt = WtO; }
  int n0 = blockIdx.x * 32, k0 = blockIdx.y * 32;
  #pragma unroll
  for (int i = 0; i < 32; i += 8) t[ty + i][tx] = W[(k0 + ty + i) * DMODEL + n0 + tx];
  __syncthreads();
  #pragma unroll
  for (int i = 0; i < 32; i += 8) Wt[(n0 + ty + i) * DMODEL + k0 + tx] = f2bf(t[tx][ty + i]);
}

// ---------- bf16 GEMM, m97 single-slab BK=32 (O-projection only, EPI=1) ------
template<int MT, int NT, int EPI>
__global__ __launch_bounds__(256) void gemm_bf16(
    const short* __restrict__ A, const short* __restrict__ Bt,
    const float* __restrict__ bq, const float* __restrict__ bk, const float* __restrict__ bv,
    short* __restrict__ qb, short* __restrict__ kb, short* __restrict__ vt,
    float* __restrict__ out)
{
  constexpr int K = DMODEL, BK = 32;
  constexpr int WM = MT / 2, WN = NT / 2;
  constexpr int TM = WM / 16, TN = WN / 16;
  constexpr int CA = MT * BK / 512;
  constexpr int CB = NT * BK / 512;
  constexpr int SME = MT * BK + NT * BK;
  __shared__ short smem[SME];
  short* la = smem;
  short* lb = smem + MT * BK;
  const int tid = threadIdx.x;
  const int wave = tid >> 6, lane = tid & 63;
  const int quad = lane >> 4, l16 = lane & 15;
  const int wr = wave >> 1, wc = wave & 1;
  const int nx = gridDim.x, ny = gridDim.y;
  const int g = blockIdx.y * nx + blockIdx.x;
  const int xcd = g & 7, rr = g >> 3;
  const int m0 = (xcd * (ny >> 3) + rr / nx) * MT;
  const int n0 = (rr % nx) * NT;
  const int arow = lane >> 2, acol = (lane & 3) * 8;

  f32x4 acc[TM][TN] = {};

  for (int k0 = 0; k0 < K; k0 += BK) {
    for (int c = wave; c < CA; c += 4) {
      const short* gp = A + (m0 + c * 16 + arow) * K + k0 + acol;
      __builtin_amdgcn_global_load_lds((__attribute__((address_space(1))) void*)gp,
                                       (__attribute__((address_space(3))) void*)(la + c * 512),
                                       16, 0, 0);
    }
    for (int c = wave; c < CB; c += 4) {
      const short* gp = Bt + (n0 + c * 16 + arow) * K + k0 + acol;
      __builtin_amdgcn_global_load_lds((__attribute__((address_space(1))) void*)gp,
                                       (__attribute__((address_space(3))) void*)(lb + c * 512),
                                       16, 0, 0);
    }
    __syncthreads();
    bf16x8 af[TM], bfr[TN];
    #pragma unroll
    for (int i = 0; i < TM; ++i)
      af[i] = *(const bf16x8*)&la[(wr * WM + i * 16 + l16) * BK + quad * 8];
    #pragma unroll
    for (int j = 0; j < TN; ++j)
      bfr[j] = *(const bf16x8*)&lb[(wc * WN + j * 16 + l16) * BK + quad * 8];
    #pragma unroll
    for (int i = 0; i < TM; ++i)
      #pragma unroll
      for (int j = 0; j < TN; ++j)
        acc[i][j] = __builtin_amdgcn_mfma_f32_16x16x32_bf16(af[i], bfr[j], acc[i][j], 0, 0, 0);
    __syncthreads();
  }

  #pragma unroll
  for (int i = 0; i < TM; ++i)
    #pragma unroll
    for (int r = 0; r < 4; ++r) {
      int mrow = m0 + wr * WM + i * 16 + quad * 4 + r;
      #pragma unroll
      for (int j = 0; j < TN; ++j)
        out[mrow * DMODEL + n0 + wc * WN + j * 16 + l16] = acc[i][j][r];
    }
  (void)bq; (void)bk; (void)bv; (void)qb; (void)kb; (void)vt;
}

// ============ 256x256 8-wave double-buffered QKV GEMM (T1-T5), v2 ============
// R1 fix: two K=32 half-phases per K-step so only 12 fragments (48 VGPR) are
// live at once -> peak ~230 VGPR; __launch_bounds__(512,2) guarantees the
// 8-wave block is schedulable (2 waves/SIMD needs <=256 VGPR). Prologue now
// drains vmcnt(0) once (removes load-group interleave soundness hole).
// T2: read-side XOR swizzle granule ^= (row&7); LDS dest stays LINEAR
//     (global_load_lds rule #21) and the SAME involution is pre-applied to
//     the GLOBAL source granule: sgl = (lane&7) ^ (lane>>3).
// T3/T4: counted vmcnt(8) in steady state; never drained mid-loop.
// T5: setprio(1) around each 32-MFMA cluster.
// T1: bijective XCD-chunked decode (192 tiles = 8 XCDs x 24, m-major).
__global__ __launch_bounds__(512, 2) void gemm_qkv(
    const short* __restrict__ A, const short* __restrict__ Bt,
    const float* __restrict__ bq, const float* __restrict__ bk, const float* __restrict__ bv,
    short* __restrict__ qb, short* __restrict__ kb, short* __restrict__ vt)
{
  constexpr int K = DMODEL, BK = 64, NT = K / BK;   // 16 K-steps
  __shared__ short lds[65536];                      // 128 KiB
  const int tid = threadIdx.x;
  const int wave = tid >> 6, lane = tid & 63;
  const int quad = lane >> 4, l16 = lane & 15;
  const int wr = wave >> 2, wc = wave & 3;          // 2(M) x 4(N) waves

  // XCD-chunked tile decode: 192 tiles = 16 m x 12 n; XCD x owns s in [24x,24x+24)
  const int g  = blockIdx.x;
  const int s  = (g & 7) * 24 + (g >> 3);
  const int m0 = (s / 12) * 256, n0 = (s % 12) * 256;

  // staging source (inverse-swizzled granule, linear LDS dest)
  const int srow = lane >> 3;                       // row within 8-row wave slab
  const int sgl  = (lane & 7) ^ srow;               // pre-swizzled k-granule
  const short* gA = A  + (m0 + wave * 8 + srow) * K + sgl * 8;
  const short* gB = Bt + (n0 + wave * 8 + srow) * K + sgl * 8;

  auto stage = [&](int buf, int k0) {               // 8 global_load_lds / wave
    short* dA = lds + buf * 32768 + wave * 512;
    short* dB = dA + 16384;
    #pragma unroll
    for (int ss = 0; ss < 4; ++ss)
      __builtin_amdgcn_global_load_lds(
          (__attribute__((address_space(1))) void*)(gA + ss * 64 * K + k0),
          (__attribute__((address_space(3))) void*)(dA + ss * 4096), 16, 0, 0);
    #pragma unroll
    for (int ss = 0; ss < 4; ++ss)
      __builtin_amdgcn_global_load_lds(
          (__attribute__((address_space(1))) void*)(gB + ss * 64 * K + k0),
          (__attribute__((address_space(3))) void*)(dB + ss * 4096), 16, 0, 0);
  };

  const int swz = l16 & 7;                          // == row&7 for all fragment rows
  f32x4 acc[8][4] = {};

  // prologue: tiles 0,1 staged; full drain once (soundness), then counted.
  stage(0, 0);
  stage(1, BK);
  asm volatile("s_waitcnt vmcnt(0)" ::: "memory");
  __builtin_amdgcn_sched_barrier(0);
  __builtin_amdgcn_s_barrier();

  for (int t = 0; t < NT; ++t) {
    const int cur = t & 1;
    const short* bA = lds + cur * 32768;
    const short* bB = bA + 16384;

    // ---- half-phase ks=0: 12 fragment reads + 32 MFMA ----
    bf16x8 a0[4], h0[4], b0[4];
    #pragma unroll
    for (int j = 0; j < 4; ++j)
      b0[j] = *(const bf16x8*)&bB[(wc * 64 + j * 16 + l16) * 64 + (quad ^ swz) * 8];
    #pragma unroll
    for (int i = 0; i < 4; ++i) {
      a0[i] = *(const bf16x8*)&bA[(wr * 128 + i * 16 + l16) * 64 + (quad ^ swz) * 8];
      h0[i] = *(const bf16x8*)&bA[(wr * 128 + 64 + i * 16 + l16) * 64 + (quad ^ swz) * 8];
    }
    __builtin_amdgcn_s_setprio(1);
    #pragma unroll
    for (int i = 0; i < 4; ++i)
      #pragma unroll
      for (int j = 0; j < 4; ++j) {
        acc[i][j]     = __builtin_amdgcn_mfma_f32_16x16x32_bf16(a0[i], b0[j], acc[i][j], 0, 0, 0);
        acc[4 + i][j] = __builtin_amdgcn_mfma_f32_16x16x32_bf16(h0[i], b0[j], acc[4 + i][j], 0, 0, 0);
      }
    __builtin_amdgcn_s_setprio(0);

    // ---- half-phase ks=1: 12 fragment reads, then buffer handoff ----
    bf16x8 a1[4], h1[4], b1[4];
    #pragma unroll
    for (int j = 0; j < 4; ++j)
      b1[j] = *(const bf16x8*)&bB[(wc * 64 + j * 16 + l16) * 64 + ((4 | quad) ^ swz) * 8];
    #pragma unroll
    for (int i = 0; i < 4; ++i) {
      a1[i] = *(const bf16x8*)&bA[(wr * 128 + i * 16 + l16) * 64 + ((4 | quad) ^ swz) * 8];
      h1[i] = *(const bf16x8*)&bA[(wr * 128 + 64 + i * 16 + l16) * 64 + ((4 | quad) ^ swz) * 8];
    }
    // all reads of buf[cur] issued; wait them into registers, sync, overwrite
    asm volatile("s_waitcnt lgkmcnt(0)" ::: "memory");
    __builtin_amdgcn_sched_barrier(0);
    __builtin_amdgcn_s_barrier();
    if (t + 2 < NT) stage(cur, (t + 2) * BK);       // fills under MFMA below

    __builtin_amdgcn_s_setprio(1);
    #pragma unroll
    for (int i = 0; i < 4; ++i)
      #pragma unroll
      for (int j = 0; j < 4; ++j) {
        acc[i][j]     = __builtin_amdgcn_mfma_f32_16x16x32_bf16(a1[i], b1[j], acc[i][j], 0, 0, 0);
        acc[4 + i][j] = __builtin_amdgcn_mfma_f32_16x16x32_bf16(h1[i], b1[j], acc[4 + i][j], 0, 0, 0);
      }
    __builtin_amdgcn_s_setprio(0);

    if (t + 1 < NT) {
      if (t + 2 < NT) asm volatile("s_waitcnt vmcnt(8)" ::: "memory");  // tile t+1 landed
      else            asm volatile("s_waitcnt vmcnt(0)" ::: "memory");  // drain tail
      __builtin_amdgcn_sched_barrier(0);
      __builtin_amdgcn_s_barrier();
    }
  }

  // ---------------- epilogue: bias + scale + head-split (+ V transpose) -----
  // Two 128-column passes (a padded 256x256 tile would exceed 128KB LDS).
  const int b = m0 >> 11, s0 = m0 & (SEQ - 1);
  const int sel = n0 >> 10;                         // 0=Q 1=K 2=V
  const int n0rel = n0 & (DMODEL - 1);
  const float* bias = (sel == 0) ? bq : (sel == 1) ? bk : bv;
  const float scl = (sel == 0) ? 0.125f * 1.44269504089f : 1.0f;
  const bool isV = (sel == 2);
  short* eT = lds;

  __syncthreads();                                  // all MFMA reads done, lds reusable
  for (int hp = 0; hp < 2; ++hp) {
    if ((wc >> 1) == hp) {                          // waves owning this col-half
      #pragma unroll
      for (int j = 0; j < 4; ++j) {
        int coll = wc * 64 + j * 16 + l16;          // 0..255 within tile
        int cl = coll & 127;                        // local col in half
        float bias_v = bias[n0rel + coll];
        #pragma unroll
        for (int i = 0; i < 8; ++i) {
          int rowb = wr * 128 + i * 16 + quad * 4;
          #pragma unroll
          for (int r = 0; r < 4; ++r) {
            short val = f2bf((acc[i][j][r] + bias_v) * scl);
            if (isV) eT[cl * 264 + rowb + r] = val; // [128 d][256 s + pad]
            else     eT[(rowb + r) * 136 + cl] = val; // [256 s][128 col + pad]
          }
        }
      }
    }
    __syncthreads();
    if (!isV) {
      short* dst = (sel == 0) ? qb : kb;
      const int rseg = tid & 15, rrow = tid >> 4;   // 16 col-granules x 32 rows
      #pragma unroll
      for (int it = 0; it < 8; ++it) {
        int row = it * 32 + rrow;
        int colg = n0rel + hp * 128 + rseg * 8;
        int h = colg >> 6, d = colg & 63;
        s16x8 v = *(const s16x8*)&eT[row * 136 + rseg * 8];
        *(s16x8*)(dst + ((b * NHEADS + h) * SEQ + s0 + row) * DHEAD + d) = v;
      }
    } else {
      const int sseg = tid & 31, dl0 = tid >> 5;    // 32 s-granules x 16 d-rows
      #pragma unroll
      for (int it = 0; it < 8; ++it) {
        int dloc = it * 16 + dl0;                   // 0..127
        int colg = n0rel + hp * 128 + dloc;
        int h = colg >> 6, d = colg & 63;
        s16x8 v = *(const s16x8*)&eT[dloc * 264 + sseg * 8];
        *(s16x8*)(vt + ((b * NHEADS + h) * DHEAD + d) * SEQ + s0 + sseg * 8) = v;
      }
    }
    __syncthreads();
  }
}

// ================= flash attention v8r: R13 core + pair-balance decode ========
__global__ __launch_bounds__(256, 2) void attn_k(
    const short* __restrict__ qbp, const short* __restrict__ kbp,
    const short* __restrict__ vtb, short* __restrict__ oP, float* __restrict__ lP)
{
  __shared__ short kls[2][8192];                    // 2 bufs x (2 chunks x 8KB)
  __shared__ short vls[2][8192];
  const int tid = threadIdx.x, wave = tid >> 6, lane = tid & 63;
  const int quad = lane >> 4, l16 = lane & 15;
  const int hi = blockIdx.x >> 8;
  const int q6 = (blockIdx.x >> 6) & 3;
  const int qg = hi ? 7 - q6 : q6;                  // 0..7
  const int half = (blockIdx.x >> 5) & 1;
  const int bh = blockIdx.x & 31;
  const int qt1 = qg * 8 + wave * 2;                // 0..62 even
  const int mF[4] = { qt1 * 16, (qt1 + 1) * 16, (126 - qt1) * 16, (127 - qt1) * 16 };
  const int nch = (127 - 8 * qg) / 4 + 1;          // block-uniform chunk count
  const short* Q  = qbp + bh * SEQ * DHEAD;
  const short* Kp = kbp + bh * SEQ * DHEAD;
  const short* Vt = vtb + bh * DHEAD * SEQ;

  bf16x8 qf[4][2];
  #pragma unroll
  for (int f = 0; f < 4; ++f) {
    qf[f][0] = *(const bf16x8*)&Q[(mF[f] + l16) * DHEAD + quad * 8];
    qf[f][1] = *(const bf16x8*)&Q[(mF[f] + l16) * DHEAD + 32 + quad * 8];
  }

  float lF[4] = {};
  f32x4 oF[4][4] = {};

  const int vdl = lane >> 3, vsl = lane & 7;        // V staging lane split

  auto stage1 = [&](int buf, int slot, int t0) {    // one 64-t chunk
    #pragma unroll
    for (int j = 0; j < 2; ++j) {
      int g = j * 4 + wave;                         // K ch-group 0..7
      const short* gp = Kp + (t0 + lane) * DHEAD + g * 8;
      __builtin_amdgcn_global_load_lds((__attribute__((address_space(1))) void*)gp,
                                       (__attribute__((address_space(3))) void*)&kls[buf][slot * 4096 + g * 512],
                                       16, 0, 0);
    }
    #pragma unroll
    for (int j = 0; j < 2; ++j) {
      int gd = j * 4 + wave;                        // V d-block 0..7
      const short* gp = Vt + (gd * 8 + vdl) * SEQ + t0 + ((vsl ^ vdl) * 8);
      __builtin_amdgcn_global_load_lds((__attribute__((address_space(1))) void*)gp,
                                       (__attribute__((address_space(3))) void*)&vls[buf][slot * 4096 + gd * 512],
                                       16, 0, 0);
    }
  };
  auto stagepair = [&](int buf, int cc) {           // chunks cc, cc+2 (owned set)
    stage1(buf, 0, cc * 64);
    if (cc + 2 < nch) stage1(buf, 1, (cc + 2) * 64);
  };

  stagepair(0, half);
  int it = 0;
  for (int cc = half; cc < nch; cc += 4, ++it) {
    __syncthreads();                                // drains stagepair; waves synced
    if (cc + 4 < nch) stagepair((it + 1) & 1, cc + 4);
    const int buf = it & 1;
    #pragma unroll
    for (int u = 0; u < 2; ++u) {                   // chunk within pair
      const int c = cc + 2 * u;
      if (c < nch) {                                // block-uniform
        const int t0 = c * 64;
        const int sb = u * 4096;
        #pragma unroll
        for (int t = 0; t < 4; ++t) {
          const int tb = t0 + t * 16;
          if (tb <= mF[3]) {                        // any fragment live (wave-uniform)
            bf16x8 kf0 = *(const bf16x8*)&kls[buf][sb + ((0 + quad) * 64 + t * 16 + l16) * 8];
            bf16x8 kf1 = *(const bf16x8*)&kls[buf][sb + ((4 + quad) * 64 + t * 16 + l16) * 8];
            s16x4 vf[4];
            {
              int gsw = ((t * 2 + (quad >> 1)) ^ (l16 & 7));
              #pragma unroll
              for (int dt = 0; dt < 4; ++dt)
                vf[dt] = *(const s16x4*)&vls[buf][sb + ((dt * 16 + l16) * 8 + gsw) * 8 + (quad & 1) * 4];
            }
            #pragma unroll
            for (int f = 0; f < 4; ++f) {
              if (tb <= mF[f]) {                    // wave-uniform
                f32x4 a = {};
                a = __builtin_amdgcn_mfma_f32_16x16x32_bf16(kf0, qf[f][0], a, 0, 0, 0);
                a = __builtin_amdgcn_mfma_f32_16x16x32_bf16(kf1, qf[f][1], a, 0, 0, 0);
                if (tb == mF[f]) {                  // diagonal: mask t > m
                  #pragma unroll
                  for (int r = 0; r < 4; ++r)
                    if (quad * 4 + r > l16) a[r] = -1e30f;
                }
                f32x4 p;
                #pragma unroll
                for (int r = 0; r < 4; ++r) p[r] = __builtin_amdgcn_exp2f(a[r]);
                lF[f] += (p[0] + p[1]) + (p[2] + p[3]);
                __hip_bfloat162 c01 = __float22bfloat162_rn(float2{p[0], p[1]});
                __hip_bfloat162 c23 = __float22bfloat162_rn(float2{p[2], p[3]});
                union { unsigned u2[2]; s16x4 s; } pu;
                pu.u2[0] = *(unsigned*)&c01; pu.u2[1] = *(unsigned*)&c23;
                #pragma unroll
                for (int dt = 0; dt < 4; ++dt)
                  oF[f][dt] = __builtin_amdgcn_mfma_f32_16x16x16bf16_1k(pu.s, vf[dt], oF[f][dt], 0, 0, 0);
              }
            }
          }
        }
      }
    }
  }

  // reduce l across quads; store partials [half][bh][s][64]
  float* lD = lP + (half * NBH + bh) * SEQ;
  short* oD = oP + ((half * NBH + bh) * SEQ) * DHEAD;
  #pragma unroll
  for (int f = 0; f < 4; ++f) {
    float l = lF[f];
    l += __shfl_xor(l, 16, 64); l += __shfl_xor(l, 32, 64);
    if (quad == 0) lD[mF[f] + l16] = l;
    #pragma unroll
    for (int r = 0; r < 4; ++r) {
      int s = mF[f] + quad * 4 + r;
      #pragma unroll
      for (int dt = 0; dt < 4; ++dt)
        oD[s * DHEAD + dt * 16 + l16] = f2bf(oF[f][dt][r]);
    }
  }
}

// ---------- merge halves: ob = (oE + oO) / (lE + lO), bf16 [b][s][h*64+d] ----
__global__ void attn_merge(const short* __restrict__ oP, const float* __restrict__ lP,
                           short* __restrict__ ob) {
  int idx = blockIdx.x * 256 + threadIdx.x;         // one thread = 8 outputs
  int d8 = idx & 7, s = (idx >> 3) & (SEQ - 1), bh = idx >> 14;
  s16x8 e = *(const s16x8*)&oP[((0   + bh) * SEQ + s) * DHEAD + d8 * 8];
  s16x8 o = *(const s16x8*)&oP[((NBH + bh) * SEQ + s) * DHEAD + d8 * 8];
  float linv = 1.0f / (lP[bh * SEQ + s] + lP[(NBH + bh) * SEQ + s]);
  s16x8 r;
  #pragma unroll
  for (int k = 0; k < 8; ++k) r[k] = f2bf((bf2f(e[k]) + bf2f(o[k])) * linv);
  int b = bh >> 4, h = bh & 15;
  *(s16x8*)&ob[(b * SEQ + s) * DMODEL + h * DHEAD + d8 * 8] = r;
}

extern "C" void kernel_launch(void* const* d_in, const int* in_sizes, int n_in,
                              void* d_out, int out_size, void* d_ws, size_t ws_size,
                              hipStream_t stream) {
  const float* x  = (const float*)d_in[0];
  const float* Wq = (const float*)d_in[1];
  const float* bq = (const float*)d_in[2];
  const float* Wk = (const float*)d_in[3];
  const float* bk = (const float*)d_in[4];
  const float* Wv = (const float*)d_in[5];
  const float* bv = (const float*)d_in[6];
  const float* Wo = (const float*)d_in[7];
  float* out = (float*)d_out;

  char* ws = (char*)d_ws;                         // ws is 256 MB (measured R7)
  short* xb  = (short*)(ws);                      // 8 MB  x bf16
  short* wtq = (short*)(ws + (8u  << 20));        // 6 MB  [Wq^T;Wk^T;Wv^T] bf16
  short* wto = (short*)(ws + (14u << 20));        // 2 MB  Wo^T bf16
  short* qb  = (short*)(ws + (16u << 20));        // 8 MB  Q (x 0.125*log2e folded)
  short* kb  = (short*)(ws + (24u << 20));        // 8 MB  K
  short* vt  = (short*)(ws + (32u << 20));        // 8 MB  V^T [bh][d][s]
  short* ob  = (short*)(ws + (40u << 20));        // 8 MB  attn out bf16
  short* oP  = (short*)(ws + (48u << 20));        // 16 MB o-partials [2][32][2048][64]
  float* lP  = (float*)(ws + (80u << 20));        // 0.5MB l-partials [2][32][2048]

  prep_fused<<<dim3(32, 32, 8), dim3(32, 8), 0, stream>>>(x, xb, Wq, Wk, Wv, Wo, wtq, wto);

  gemm_qkv<<<dim3(192), 512, 0, stream>>>(xb, wtq, bq, bk, bv, qb, kb, vt);

  attn_k<<<8 * NBH * 2, 256, 0, stream>>>(qb, kb, vt, oP, lP);
  attn_merge<<<NBH * SEQ * 8 / 256, 256, 0, stream>>>(oP, lP, ob);

  gemm_bf16<64, 128, 1><<<dim3(DMODEL / 128, MROWS / 64), 256, 0, stream>>>(
      ob, wto, nullptr, nullptr, nullptr, nullptr, nullptr, nullptr, out);
}